// Round 6
// baseline (429.612 us; speedup 1.0000x reference)
//
#include <hip/hip_runtime.h>
#include <cmath>

#define NTOK 3072
#define NBLK 3
#define PSS 133   // ps LDS stride: %32 == 5 -> conflict-free PV reads

__device__ __forceinline__ float sig(float v) { return 1.0f / (1.0f + expf(-v)); }

struct Params {
    const float *ql, *cl, *plm;
    const float *ada_g_w, *ada_g_b, *ada_b_w;
    const float *wq, *bq, *wk, *wv;
    const float *z_ln_g, *z_ln_b, *wz;
    const float *wg, *wo, *sg_w, *sg_b;
    const float *ada2_g_w, *ada2_g_b, *ada2_b_w;
    const float *ff1, *ff2, *ff3, *sg2_w, *sg2_b;
    float *ln_a, *attn, *qkvg, *ffb, *zb;
    float *out;
};

// 32-lane-subgroup row LN of 4 register values (cols cq..cq+3 of a 128-col row)
__device__ __forceinline__ float4 ln_row32(float4 v)
{
    float s = v.x + v.y + v.z + v.w;
#pragma unroll
    for (int m = 1; m < 32; m <<= 1) s += __shfl_xor(s, m);
    float mean = s * (1.0f / 128.0f);
    float d0 = v.x - mean, d1 = v.y - mean, d2 = v.z - mean, d3 = v.w - mean;
    float var = d0 * d0 + d1 * d1 + d2 * d2 + d3 * d3;
#pragma unroll
    for (int m = 1; m < 32; m <<= 1) var += __shfl_xor(var, m);
    float rs = 1.0f / sqrtf(var * (1.0f / 128.0f) + 1e-5f);
    return make_float4(d0 * rs, d1 * rs, d2 * rs, d3 * rs);
}

// ================= k1: pre  (LN(cl) -> gate/beta -> x|y -> qkvg | ffb; i==0 also zb) ==========
// grid 768 = 8 XCD x 48 row-tiles(8) x 2 u;  u=0: x->q,k,v,g   u=1: y->ff1,ff2
__global__ __launch_bounds__(256) void k1_pre(Params P, int i)
{
    __shared__ __align__(16) float smA[8 * 132];   // LN(cl) tile
    __shared__ __align__(16) float smX[8 * 132];   // x or y tile
    __shared__ __align__(16) float wzg[204];
    int tid = threadIdx.x, bid = blockIdx.x;
    int x8 = bid & 7, g = bid >> 3;
    int u = g & 1, tl = g >> 1;
    int row0 = x8 * 384 + tl * 8;
    int lane = tid & 63, wid = tid >> 6;
    int cq = (lane & 31) * 4;
    int r1 = wid * 2 + (lane >> 5);          // 8 row slots; same half-wave stages/owns row r1
    int row = row0 + r1;

    if (i == 0) {
        if (tid < 192) {
            int i3 = tid >> 6, rem = tid & 63, c = rem >> 2, h = rem & 3;
            wzg[(i3 * 16 + c) * 4 + h] = P.z_ln_g[i3 * 16 + c] * P.wz[(i3 * 16 + c) * 4 + h];
        }
        if (tid < 12) {
            int i3 = tid >> 2, h = tid & 3;
            float s = 0.0f;
            for (int c = 0; c < 16; c++) s += P.z_ln_b[i3 * 16 + c] * P.wz[(i3 * 16 + c) * 4 + h];
            wzg[192 + tid] = s;
        }
    }
    // stage cl tile (mapping == ownership: half-wave of row r1 stages row r1)
    {
        int fo = tid * 4, r = fo >> 7, c = fo & 127;
        *(float4*)&smA[r * 132 + c] = *(const float4*)&P.cl[(size_t)(row0 + r) * 128 + c];
    }
    __syncthreads();
    // LN rows in place (own-row, 32-lane subgroup)
    {
        float4 c4 = *(float4*)&smA[r1 * 132 + cq];
        *(float4*)&smA[r1 * 132 + cq] = ln_row32(c4);
    }
    __syncthreads();

    // GEMM1: gate + beta from s_ln tile
    const float* Wg = (u ? P.ada2_g_w : P.ada_g_w) + (size_t)i * 16384 + cq;
    const float* Wb = (u ? P.ada2_b_w : P.ada_b_w) + (size_t)i * 16384 + cq;
    const float* bg = (u ? P.ada2_g_b : P.ada_g_b) + (size_t)i * 128;
    float ga[4] = {}, ba[4] = {};
#pragma unroll 4
    for (int k = 0; k < 128; k++) {
        float4 wg4 = *(const float4*)(Wg + (size_t)k * 128);
        float4 wb4 = *(const float4*)(Wb + (size_t)k * 128);
        float a = smA[r1 * 132 + k];
        ga[0] = fmaf(a, wg4.x, ga[0]); ga[1] = fmaf(a, wg4.y, ga[1]);
        ga[2] = fmaf(a, wg4.z, ga[2]); ga[3] = fmaf(a, wg4.w, ga[3]);
        ba[0] = fmaf(a, wb4.x, ba[0]); ba[1] = fmaf(a, wb4.y, ba[1]);
        ba[2] = fmaf(a, wb4.z, ba[2]); ba[3] = fmaf(a, wb4.w, ba[3]);
    }
    // ln_a: i==0 -> LN(ql row) in-register; else read buffer
    float4 ln4;
    if (i == 0) {
        float4 q4 = *(const float4*)&P.ql[(size_t)row * 128 + cq];
        ln4 = ln_row32(q4);
    } else {
        ln4 = *(const float4*)&P.ln_a[(size_t)row * 128 + cq];
    }
    {
        float4 bg4 = *(const float4*)&bg[cq];
        float4 xo;
        xo.x = sig(ga[0] + bg4.x) * ln4.x + ba[0];
        xo.y = sig(ga[1] + bg4.y) * ln4.y + ba[1];
        xo.z = sig(ga[2] + bg4.z) * ln4.z + ba[2];
        xo.w = sig(ga[3] + bg4.w) * ln4.w + ba[3];
        *(float4*)&smX[r1 * 132 + cq] = xo;   // own half-wave; no barrier needed
    }
    __syncthreads();   // safety

    if (u == 0) {
        const float* Wq = P.wq + (size_t)i * 16384 + cq;
        const float* Wk = P.wk + (size_t)i * 16384 + cq;
        const float* Wv = P.wv + (size_t)i * 16384 + cq;
        const float* Wgt = P.wg + (size_t)i * 16384 + cq;
        float aq[4] = {}, ak[4] = {}, av[4] = {}, ag[4] = {};
#pragma unroll 2
        for (int k = 0; k < 128; k++) {
            float4 w1 = *(const float4*)(Wq + (size_t)k * 128);
            float4 w2 = *(const float4*)(Wk + (size_t)k * 128);
            float4 w3 = *(const float4*)(Wv + (size_t)k * 128);
            float4 w4 = *(const float4*)(Wgt + (size_t)k * 128);
            float a = smX[r1 * 132 + k];
            aq[0] = fmaf(a, w1.x, aq[0]); aq[1] = fmaf(a, w1.y, aq[1]);
            aq[2] = fmaf(a, w1.z, aq[2]); aq[3] = fmaf(a, w1.w, aq[3]);
            ak[0] = fmaf(a, w2.x, ak[0]); ak[1] = fmaf(a, w2.y, ak[1]);
            ak[2] = fmaf(a, w2.z, ak[2]); ak[3] = fmaf(a, w2.w, ak[3]);
            av[0] = fmaf(a, w3.x, av[0]); av[1] = fmaf(a, w3.y, av[1]);
            av[2] = fmaf(a, w3.z, av[2]); av[3] = fmaf(a, w3.w, av[3]);
            ag[0] = fmaf(a, w4.x, ag[0]); ag[1] = fmaf(a, w4.y, ag[1]);
            ag[2] = fmaf(a, w4.z, ag[2]); ag[3] = fmaf(a, w4.w, ag[3]);
        }
        float4 bq4 = *(const float4*)&P.bq[(size_t)i * 128 + cq];
        float* qr = &P.qkvg[(size_t)row * 512 + cq];
        *(float4*)(qr)       = make_float4(aq[0] + bq4.x, aq[1] + bq4.y, aq[2] + bq4.z, aq[3] + bq4.w);
        *(float4*)(qr + 128) = make_float4(ak[0], ak[1], ak[2], ak[3]);
        *(float4*)(qr + 256) = make_float4(av[0], av[1], av[2], av[3]);
        *(float4*)(qr + 384) = make_float4(ag[0], ag[1], ag[2], ag[3]);
    } else {
        const float* F1 = P.ff1 + (size_t)i * 32768 + cq;
        const float* F2 = P.ff2 + (size_t)i * 32768 + cq;
        float a1l[4] = {}, a1h[4] = {}, a2l[4] = {}, a2h[4] = {};
#pragma unroll 2
        for (int k = 0; k < 128; k++) {
            float4 w1 = *(const float4*)(F1 + (size_t)k * 256);
            float4 w2 = *(const float4*)(F1 + (size_t)k * 256 + 128);
            float4 w3 = *(const float4*)(F2 + (size_t)k * 256);
            float4 w4 = *(const float4*)(F2 + (size_t)k * 256 + 128);
            float a = smX[r1 * 132 + k];
            a1l[0] = fmaf(a, w1.x, a1l[0]); a1l[1] = fmaf(a, w1.y, a1l[1]);
            a1l[2] = fmaf(a, w1.z, a1l[2]); a1l[3] = fmaf(a, w1.w, a1l[3]);
            a1h[0] = fmaf(a, w2.x, a1h[0]); a1h[1] = fmaf(a, w2.y, a1h[1]);
            a1h[2] = fmaf(a, w2.z, a1h[2]); a1h[3] = fmaf(a, w2.w, a1h[3]);
            a2l[0] = fmaf(a, w3.x, a2l[0]); a2l[1] = fmaf(a, w3.y, a2l[1]);
            a2l[2] = fmaf(a, w3.z, a2l[2]); a2l[3] = fmaf(a, w3.w, a2l[3]);
            a2h[0] = fmaf(a, w4.x, a2h[0]); a2h[1] = fmaf(a, w4.y, a2h[1]);
            a2h[2] = fmaf(a, w4.z, a2h[2]); a2h[3] = fmaf(a, w4.w, a2h[3]);
        }
        float* fr = &P.ffb[(size_t)row * 256 + cq];
        float4 ol, oh;
        ol.x = a1l[0] * sig(a1l[0]) * a2l[0]; ol.y = a1l[1] * sig(a1l[1]) * a2l[1];
        ol.z = a1l[2] * sig(a1l[2]) * a2l[2]; ol.w = a1l[3] * sig(a1l[3]) * a2l[3];
        oh.x = a1h[0] * sig(a1h[0]) * a2h[0]; oh.y = a1h[1] * sig(a1h[1]) * a2h[1];
        oh.z = a1h[2] * sig(a1h[2]) * a2h[2]; oh.w = a1h[3] * sig(a1h[3]) * a2h[3];
        *(float4*)(fr)       = ol;
        *(float4*)(fr + 128) = oh;
    }

    // ---- zb for these 8 rows (all 3 layers), heads split by u; only at i==0 ----
    if (i == 0) {
        __syncthreads();
        int j = row0 >> 5;
        int kstart = max(0, j * 32 - 48);
        int W = min(NTOK, j * 32 + 80) - kstart;
        for (int p = tid; p < 8 * 128; p += 256) {
            int qi = p >> 7, kk = p & 127;
            if (kk >= W) continue;
            int q = row0 + qi;
            const float* src = P.plm + ((size_t)q * NTOK + (size_t)(kstart + kk)) * 16;
            float xv[16];
            *(float4*)(xv + 0)  = *(const float4*)(src + 0);
            *(float4*)(xv + 4)  = *(const float4*)(src + 4);
            *(float4*)(xv + 8)  = *(const float4*)(src + 8);
            *(float4*)(xv + 12) = *(const float4*)(src + 12);
            float s = 0.0f;
#pragma unroll
            for (int c = 0; c < 16; c++) s += xv[c];
            float mean = s * (1.0f / 16.0f);
            float var = 0.0f;
#pragma unroll
            for (int c = 0; c < 16; c++) { float d = xv[c] - mean; var += d * d; }
            float rs = 1.0f / sqrtf(var * (1.0f / 16.0f) + 1e-5f);
#pragma unroll
            for (int c = 0; c < 16; c++) xv[c] = (xv[c] - mean) * rs;
#pragma unroll
            for (int i3 = 0; i3 < NBLK; i3++) {
#pragma unroll
                for (int hh = 0; hh < 2; hh++) {
                    int h = u * 2 + hh;
                    float o = wzg[192 + i3 * 4 + h];
#pragma unroll
                    for (int c = 0; c < 16; c++) o = fmaf(xv[c], wzg[(i3 * 16 + c) * 4 + h], o);
                    P.zb[((size_t)(i3 * 4 + h) * NTOK + q) * 128 + kk] = o;
                }
            }
        }
    }
}

// ================= k2: local attention (grid 384 = 8 XCD x 12 j x 4 h) =================
__global__ __launch_bounds__(256) void k2_attn(Params P, int i)
{
    __shared__ __align__(16) float ks[128 * 36];
    __shared__ __align__(16) float vs[128 * 36];
    __shared__ float ps[32 * PSS];
    int tid = threadIdx.x, bid = blockIdx.x;
    int x8 = bid & 7, g = bid >> 3;
    int h = g / 12, jl = g % 12;
    int j = x8 * 12 + jl;
    int q0 = j * 32;
    int kstart = max(0, q0 - 48);
    int W = min(NTOK, q0 + 80) - kstart;
    for (int idx = tid; idx < W * 8; idx += 256) {
        int kk = idx >> 3, d = (idx & 7) * 4;
        const float* base = &P.qkvg[(size_t)(kstart + kk) * 512 + 128 + h * 32 + d];
        float4 tK = *(const float4*)base;
        float4 tV = *(const float4*)(base + 128);
        *(float4*)&ks[kk * 36 + d] = tK;
        *(float4*)&vs[kk * 36 + d] = tV;
    }
    const float* zbase = &P.zb[((size_t)(i * 4 + h) * NTOK + q0) * 128];
#pragma unroll
    for (int it = 0; it < 4; it++) {
        int idx = tid + it * 256;
        int r = idx >> 5, c4 = (idx & 31) * 4;
        float4 z4 = *(const float4*)&zbase[(size_t)r * 128 + c4];
        ps[r * PSS + c4]     = z4.x;
        ps[r * PSS + c4 + 1] = z4.y;
        ps[r * PSS + c4 + 2] = z4.z;
        ps[r * PSS + c4 + 3] = z4.w;
    }
    int qi = tid & 31, kg = tid >> 5;
    float qreg[32];
    {
        const float* qp = &P.qkvg[(size_t)(q0 + qi) * 512 + h * 32];
#pragma unroll
        for (int d4 = 0; d4 < 8; d4++) {
            float4 tq = *(const float4*)(qp + d4 * 4);
            qreg[d4 * 4] = tq.x; qreg[d4 * 4 + 1] = tq.y;
            qreg[d4 * 4 + 2] = tq.z; qreg[d4 * 4 + 3] = tq.w;
        }
    }
    __syncthreads();
    const float scale = 0.17677669529663687f;  // 1/sqrt(32)
#pragma unroll
    for (int t2 = 0; t2 < 16; t2++) {
        int kk = kg + t2 * 8;
        if (kk < W) {
            float acc = 0.0f;
#pragma unroll
            for (int d4 = 0; d4 < 8; d4++) {
                float4 kv = *(const float4*)&ks[kk * 36 + d4 * 4];
                acc = fmaf(qreg[d4 * 4 + 0], kv.x, acc);
                acc = fmaf(qreg[d4 * 4 + 1], kv.y, acc);
                acc = fmaf(qreg[d4 * 4 + 2], kv.z, acc);
                acc = fmaf(qreg[d4 * 4 + 3], kv.w, acc);
            }
            ps[qi * PSS + kk] = fmaf(acc, scale, ps[qi * PSS + kk]);
        }
    }
    __syncthreads();
    {
        int row = tid >> 3, sub = tid & 7;
        float m = -3.0e38f;
        for (int kk = sub; kk < W; kk += 8) m = fmaxf(m, ps[row * PSS + kk]);
#pragma unroll
        for (int s2 = 1; s2 < 8; s2 <<= 1) m = fmaxf(m, __shfl_xor(m, s2));
        float ssum = 0.0f;
        for (int kk = sub; kk < W; kk += 8) {
            float e = expf(ps[row * PSS + kk] - m);
            ps[row * PSS + kk] = e; ssum += e;
        }
#pragma unroll
        for (int s2 = 1; s2 < 8; s2 <<= 1) ssum += __shfl_xor(ssum, s2);
        float rinv = 1.0f / ssum;
        for (int kk = sub; kk < W; kk += 8) ps[row * PSS + kk] *= rinv;
    }
    __syncthreads();
    {
        int dg = tid >> 5, d0 = dg * 4;
        float o0 = 0, o1 = 0, o2 = 0, o3 = 0;
#pragma unroll 2
        for (int kk = 0; kk < W; kk++) {
            float pv = ps[qi * PSS + kk];
            float4 v4 = *(const float4*)&vs[kk * 36 + d0];
            o0 = fmaf(pv, v4.x, o0);
            o1 = fmaf(pv, v4.y, o1);
            o2 = fmaf(pv, v4.z, o2);
            o3 = fmaf(pv, v4.w, o3);
        }
        float4 g4 = *(const float4*)&P.qkvg[(size_t)(q0 + qi) * 512 + 384 + h * 32 + d0];
        float4 r;
        r.x = o0 * sig(g4.x); r.y = o1 * sig(g4.y);
        r.z = o2 * sig(g4.z); r.w = o3 * sig(g4.w);
        *(float4*)&P.attn[(size_t)(q0 + qi) * 128 + h * 32 + d0] = r;
    }
}

// ================= k3: post (grid 384 = 8 XCD x 48 row-tiles(8)) =================
__global__ __launch_bounds__(256) void k3_post(Params P, int i)
{
    __shared__ __align__(16) float smA[8 * 132];   // LN(cl)
    __shared__ __align__(16) float smB[8 * 132];   // attn
    __shared__ __align__(16) float smC[8 * 260];   // ffb
    int tid = threadIdx.x, bid = blockIdx.x;
    int x8 = bid & 7, g = bid >> 3;
    int row0 = x8 * 384 + g * 8;
    int lane = tid & 63, wid = tid >> 6;
    int cq = (lane & 31) * 4;
    int r1 = wid * 2 + (lane >> 5);
    {
        int fo = tid * 4, r = fo >> 7, c = fo & 127;
        *(float4*)&smA[r * 132 + c] = *(const float4*)&P.cl[(size_t)(row0 + r) * 128 + c];
        *(float4*)&smB[r * 132 + c] = *(const float4*)&P.attn[(size_t)(row0 + r) * 128 + c];
    }
#pragma unroll
    for (int it = 0; it < 2; it++) {
        int fo = (tid + it * 256) * 4;
        int r = fo >> 8, c = fo & 255;
        *(float4*)&smC[r * 260 + c] = *(const float4*)&P.ffb[(size_t)(row0 + r) * 256 + c];
    }
    __syncthreads();
    {   // LN(cl) rows in place (own-row, pre-barrier-safe since stage map == ownership)
        float4 c4 = *(float4*)&smA[r1 * 132 + cq];
        *(float4*)&smA[r1 * 132 + cq] = ln_row32(c4);
    }
    __syncthreads();
    const float* sgw  = P.sg_w  + (size_t)i * 16384 + cq;
    const float* sg2w = P.sg2_w + (size_t)i * 16384 + cq;
    const float* wo_i = P.wo    + (size_t)i * 16384 + cq;
    const float* f3   = P.ff3   + (size_t)i * 32768 + cq;
    float aG[4] = {}, aG2[4] = {}, aO[4] = {}, aT[4] = {};
#pragma unroll 2
    for (int k = 0; k < 128; k++) {
        float4 w1 = *(const float4*)(sgw  + (size_t)k * 128);
        float4 w2 = *(const float4*)(sg2w + (size_t)k * 128);
        float4 w3 = *(const float4*)(wo_i + (size_t)k * 128);
        float as = smA[r1 * 132 + k];
        float aa = smB[r1 * 132 + k];
        aG[0]  = fmaf(as, w1.x, aG[0]);  aG[1]  = fmaf(as, w1.y, aG[1]);
        aG[2]  = fmaf(as, w1.z, aG[2]);  aG[3]  = fmaf(as, w1.w, aG[3]);
        aG2[0] = fmaf(as, w2.x, aG2[0]); aG2[1] = fmaf(as, w2.y, aG2[1]);
        aG2[2] = fmaf(as, w2.z, aG2[2]); aG2[3] = fmaf(as, w2.w, aG2[3]);
        aO[0]  = fmaf(aa, w3.x, aO[0]);  aO[1]  = fmaf(aa, w3.y, aO[1]);
        aO[2]  = fmaf(aa, w3.z, aO[2]);  aO[3]  = fmaf(aa, w3.w, aO[3]);
    }
#pragma unroll 2
    for (int k = 0; k < 256; k++) {
        float4 w4 = *(const float4*)(f3 + (size_t)k * 128);
        float ac = smC[r1 * 260 + k];
        aT[0] = fmaf(ac, w4.x, aT[0]); aT[1] = fmaf(ac, w4.y, aT[1]);
        aT[2] = fmaf(ac, w4.z, aT[2]); aT[3] = fmaf(ac, w4.w, aT[3]);
    }
    float4 bv  = *(const float4*)&P.sg_b [(size_t)i * 128 + cq];
    float4 bv2 = *(const float4*)&P.sg2_b[(size_t)i * 128 + cq];
    float4 o;
    o.x = sig(aG[0] + bv.x) * aO[0] + sig(aG2[0] + bv2.x) * aT[0];
    o.y = sig(aG[1] + bv.y) * aO[1] + sig(aG2[1] + bv2.y) * aT[1];
    o.z = sig(aG[2] + bv.z) * aO[2] + sig(aG2[2] + bv2.z) * aT[2];
    o.w = sig(aG[3] + bv.w) * aO[3] + sig(aG2[3] + bv2.w) * aT[3];
    int row = row0 + r1;
    if (i == NBLK - 1) {
        *(float4*)&P.out[(size_t)row * 128 + cq] = o;
    } else {
        *(float4*)&P.ln_a[(size_t)row * 128 + cq] = ln_row32(o);
    }
}

extern "C" void kernel_launch(void* const* d_in, const int* in_sizes, int n_in,
                              void* d_out, int out_size, void* d_ws, size_t ws_size,
                              hipStream_t stream)
{
    Params P;
    P.ql       = (const float*)d_in[0];
    P.cl       = (const float*)d_in[1];
    P.plm      = (const float*)d_in[2];
    P.ada_g_w  = (const float*)d_in[3];
    P.ada_g_b  = (const float*)d_in[4];
    P.ada_b_w  = (const float*)d_in[5];
    P.wq       = (const float*)d_in[6];
    P.bq       = (const float*)d_in[7];
    P.wk       = (const float*)d_in[8];
    P.wv       = (const float*)d_in[9];
    P.z_ln_g   = (const float*)d_in[10];
    P.z_ln_b   = (const float*)d_in[11];
    P.wz       = (const float*)d_in[12];
    P.wg       = (const float*)d_in[13];
    P.wo       = (const float*)d_in[14];
    P.sg_w     = (const float*)d_in[15];
    P.sg_b     = (const float*)d_in[16];
    P.ada2_g_w = (const float*)d_in[17];
    P.ada2_g_b = (const float*)d_in[18];
    P.ada2_b_w = (const float*)d_in[19];
    P.ff1      = (const float*)d_in[20];
    P.ff2      = (const float*)d_in[21];
    P.ff3      = (const float*)d_in[22];
    P.sg2_w    = (const float*)d_in[23];
    P.sg2_b    = (const float*)d_in[24];

    float* ws = (float*)d_ws;
    const size_t NC = (size_t)NTOK * 128;
    P.ln_a = ws;
    P.attn = ws + NC;
    P.qkvg = ws + 2 * NC;   // N x 512
    P.ffb  = ws + 6 * NC;   // N x 256
    P.zb   = ws + 8 * NC;   // 3 x 4 x N x 128
    P.out  = (float*)d_out;

    for (int i = 0; i < NBLK; i++) {
        k1_pre<<<768, 256, 0, stream>>>(P, i);
        k2_attn<<<384, 256, 0, stream>>>(P, i);
        k3_post<<<384, 256, 0, stream>>>(P, i);
    }
}

// Round 7
// 415.580 us; speedup vs baseline: 1.0338x; 1.0338x over previous
//
#include <hip/hip_runtime.h>
#include <cmath>

#define NTOK 3072
#define NBLK 3
#define PSS 133   // ps LDS stride: %32 == 5 -> conflict-free reads

__device__ __forceinline__ float sig(float v) { return 1.0f / (1.0f + expf(-v)); }

struct Params {
    const float *ql, *cl, *plm;
    const float *ada_g_w, *ada_g_b, *ada_b_w;
    const float *wq, *bq, *wk, *wv;
    const float *z_ln_g, *z_ln_b, *wz;
    const float *wg, *wo, *sg_w, *sg_b;
    const float *ada2_g_w, *ada2_g_b, *ada2_b_w;
    const float *ff1, *ff2, *ff3, *sg2_w, *sg2_b;
    float *anew, *attn, *qkvg, *ffb, *zb;
    float *out;
};

// 32-lane-subgroup row LN of 4 register values (cols cq..cq+3 of a 128-col row)
__device__ __forceinline__ float4 ln_row32(float4 v)
{
    float s = v.x + v.y + v.z + v.w;
#pragma unroll
    for (int m = 1; m < 32; m <<= 1) s += __shfl_xor(s, m);
    float mean = s * (1.0f / 128.0f);
    float d0 = v.x - mean, d1 = v.y - mean, d2 = v.z - mean, d3 = v.w - mean;
    float var = d0 * d0 + d1 * d1 + d2 * d2 + d3 * d3;
#pragma unroll
    for (int m = 1; m < 32; m <<= 1) var += __shfl_xor(var, m);
    float rs = 1.0f / sqrtf(var * (1.0f / 128.0f) + 1e-5f);
    return make_float4(d0 * rs, d1 * rs, d2 * rs, d3 * rs);
}

// ================= k1: pre =================
// grid 768 = 8 XCD x 24 tiles(16 rows) x 4 units
//   u=0: x -> wq,wk   u=1: x -> wv,wg   u=2: y -> ff[0:128]   u=3: y -> ff[128:256]
// i==0: also zb for kk-range [u*32, u*32+32)
__global__ __launch_bounds__(256) void k1_pre(Params P, int i)
{
    __shared__ __align__(16) float smA[16 * 132];   // LN(cl) tile
    __shared__ __align__(16) float smX[16 * 132];   // x or y tile
    __shared__ __align__(16) float wzg[204];
    int tid = threadIdx.x, bid = blockIdx.x;
    int x8 = bid & 7, g = bid >> 3;
    int u = g & 3, tl = g >> 2;
    int row0 = x8 * 384 + tl * 16;
    int lane = tid & 63;
    int cq = (lane & 31) * 4;
    int hw = tid >> 5;            // 8 half-waves
    int r0 = hw * 2;              // rows r0, r0+1 of the 16-row tile

    if (i == 0) {
        if (tid < 192) {
            int i3 = tid >> 6, rem = tid & 63, c = rem >> 2, h = rem & 3;
            wzg[(i3 * 16 + c) * 4 + h] = P.z_ln_g[i3 * 16 + c] * P.wz[(i3 * 16 + c) * 4 + h];
        }
        if (tid < 12) {
            int i3 = tid >> 2, h = tid & 3;
            float s = 0.0f;
            for (int c = 0; c < 16; c++) s += P.z_ln_b[i3 * 16 + c] * P.wz[(i3 * 16 + c) * 4 + h];
            wzg[192 + tid] = s;
        }
    }
    // stage cl tile
#pragma unroll
    for (int it = 0; it < 2; it++) {
        int fo = (tid + it * 256) * 4;
        int r = fo >> 7, c = fo & 127;
        *(float4*)&smA[r * 132 + c] = *(const float4*)&P.cl[(size_t)(row0 + r) * 128 + c];
    }
    __syncthreads();
    // LN in place (half-wave hw owns rows r0, r0+1; lanes cover cols)
    {
        float4 n0 = ln_row32(*(float4*)&smA[r0 * 132 + cq]);
        float4 n1 = ln_row32(*(float4*)&smA[(r0 + 1) * 132 + cq]);
        *(float4*)&smA[r0 * 132 + cq] = n0;
        *(float4*)&smA[(r0 + 1) * 132 + cq] = n1;
    }
    __syncthreads();

    // GEMM1: gate + beta for rows r0, r0+1
    const float* Wg = (u < 2 ? P.ada_g_w : P.ada2_g_w) + (size_t)i * 16384 + cq;
    const float* Wb = (u < 2 ? P.ada_b_w : P.ada2_b_w) + (size_t)i * 16384 + cq;
    const float* bg = (u < 2 ? P.ada_g_b : P.ada2_g_b) + (size_t)i * 128;
    float g0[4] = {}, g1[4] = {}, b0[4] = {}, b1[4] = {};
#pragma unroll 4
    for (int k = 0; k < 128; k++) {
        float4 wg4 = *(const float4*)(Wg + (size_t)k * 128);
        float4 wb4 = *(const float4*)(Wb + (size_t)k * 128);
        float a0 = smA[r0 * 132 + k];
        float a1 = smA[r0 * 132 + 132 + k];
        g0[0] = fmaf(a0, wg4.x, g0[0]); g0[1] = fmaf(a0, wg4.y, g0[1]);
        g0[2] = fmaf(a0, wg4.z, g0[2]); g0[3] = fmaf(a0, wg4.w, g0[3]);
        g1[0] = fmaf(a1, wg4.x, g1[0]); g1[1] = fmaf(a1, wg4.y, g1[1]);
        g1[2] = fmaf(a1, wg4.z, g1[2]); g1[3] = fmaf(a1, wg4.w, g1[3]);
        b0[0] = fmaf(a0, wb4.x, b0[0]); b0[1] = fmaf(a0, wb4.y, b0[1]);
        b0[2] = fmaf(a0, wb4.z, b0[2]); b0[3] = fmaf(a0, wb4.w, b0[3]);
        b1[0] = fmaf(a1, wb4.x, b1[0]); b1[1] = fmaf(a1, wb4.y, b1[1]);
        b1[2] = fmaf(a1, wb4.z, b1[2]); b1[3] = fmaf(a1, wb4.w, b1[3]);
    }
    // LN(a_prev) rows in-register
    const float* aprev = (i == 0) ? P.ql : P.anew;
    float4 ln0 = ln_row32(*(const float4*)&aprev[(size_t)(row0 + r0) * 128 + cq]);
    float4 ln1 = ln_row32(*(const float4*)&aprev[(size_t)(row0 + r0 + 1) * 128 + cq]);
    {
        float4 bg4 = *(const float4*)&bg[cq];
        float4 xo0, xo1;
        xo0.x = sig(g0[0] + bg4.x) * ln0.x + b0[0];
        xo0.y = sig(g0[1] + bg4.y) * ln0.y + b0[1];
        xo0.z = sig(g0[2] + bg4.z) * ln0.z + b0[2];
        xo0.w = sig(g0[3] + bg4.w) * ln0.w + b0[3];
        xo1.x = sig(g1[0] + bg4.x) * ln1.x + b1[0];
        xo1.y = sig(g1[1] + bg4.y) * ln1.y + b1[1];
        xo1.z = sig(g1[2] + bg4.z) * ln1.z + b1[2];
        xo1.w = sig(g1[3] + bg4.w) * ln1.w + b1[3];
        *(float4*)&smX[r0 * 132 + cq] = xo0;
        *(float4*)&smX[(r0 + 1) * 132 + cq] = xo1;
    }
    __syncthreads();

    // GEMM2: two weight matrices from the x/y tile
    const float* W1; const float* W2; int ws2;
    if (u == 0)      { W1 = P.wq + (size_t)i * 16384; W2 = P.wk + (size_t)i * 16384; ws2 = 128; }
    else if (u == 1) { W1 = P.wv + (size_t)i * 16384; W2 = P.wg + (size_t)i * 16384; ws2 = 128; }
    else             { int ch = (u - 2) * 128;
                       W1 = P.ff1 + (size_t)i * 32768 + ch; W2 = P.ff2 + (size_t)i * 32768 + ch; ws2 = 256; }
    W1 += cq; W2 += cq;
    float c10[4] = {}, c11[4] = {}, c20[4] = {}, c21[4] = {};
#pragma unroll 4
    for (int k = 0; k < 128; k++) {
        float4 w14 = *(const float4*)(W1 + (size_t)k * ws2);
        float4 w24 = *(const float4*)(W2 + (size_t)k * ws2);
        float a0 = smX[r0 * 132 + k];
        float a1 = smX[r0 * 132 + 132 + k];
        c10[0] = fmaf(a0, w14.x, c10[0]); c10[1] = fmaf(a0, w14.y, c10[1]);
        c10[2] = fmaf(a0, w14.z, c10[2]); c10[3] = fmaf(a0, w14.w, c10[3]);
        c11[0] = fmaf(a1, w14.x, c11[0]); c11[1] = fmaf(a1, w14.y, c11[1]);
        c11[2] = fmaf(a1, w14.z, c11[2]); c11[3] = fmaf(a1, w14.w, c11[3]);
        c20[0] = fmaf(a0, w24.x, c20[0]); c20[1] = fmaf(a0, w24.y, c20[1]);
        c20[2] = fmaf(a0, w24.z, c20[2]); c20[3] = fmaf(a0, w24.w, c20[3]);
        c21[0] = fmaf(a1, w24.x, c21[0]); c21[1] = fmaf(a1, w24.y, c21[1]);
        c21[2] = fmaf(a1, w24.z, c21[2]); c21[3] = fmaf(a1, w24.w, c21[3]);
    }
    int rA = row0 + r0, rB = rA + 1;
    if (u < 2) {
        int obase = u * 256;
        float4 bq4 = make_float4(0, 0, 0, 0);
        if (u == 0) bq4 = *(const float4*)&P.bq[(size_t)i * 128 + cq];
        *(float4*)&P.qkvg[(size_t)rA * 512 + obase + cq] =
            make_float4(c10[0] + bq4.x, c10[1] + bq4.y, c10[2] + bq4.z, c10[3] + bq4.w);
        *(float4*)&P.qkvg[(size_t)rB * 512 + obase + cq] =
            make_float4(c11[0] + bq4.x, c11[1] + bq4.y, c11[2] + bq4.z, c11[3] + bq4.w);
        *(float4*)&P.qkvg[(size_t)rA * 512 + obase + 128 + cq] = make_float4(c20[0], c20[1], c20[2], c20[3]);
        *(float4*)&P.qkvg[(size_t)rB * 512 + obase + 128 + cq] = make_float4(c21[0], c21[1], c21[2], c21[3]);
    } else {
        int ch = (u - 2) * 128;
        float4 oA, oB;
        oA.x = c10[0] * sig(c10[0]) * c20[0]; oA.y = c10[1] * sig(c10[1]) * c20[1];
        oA.z = c10[2] * sig(c10[2]) * c20[2]; oA.w = c10[3] * sig(c10[3]) * c20[3];
        oB.x = c11[0] * sig(c11[0]) * c21[0]; oB.y = c11[1] * sig(c11[1]) * c21[1];
        oB.z = c11[2] * sig(c11[2]) * c21[2]; oB.w = c11[3] * sig(c11[3]) * c21[3];
        *(float4*)&P.ffb[(size_t)rA * 256 + ch + cq] = oA;
        *(float4*)&P.ffb[(size_t)rB * 256 + ch + cq] = oB;
    }

    // ---- zb (i==0 only): this tile's 16 rows, kk-range [u*32, u*32+32) ----
    if (i == 0) {
        int j = row0 >> 5;
        int kstart = max(0, j * 32 - 48);
        int W = min(NTOK, j * 32 + 80) - kstart;
#pragma unroll
        for (int it = 0; it < 2; it++) {
            int idx = tid + it * 256;
            int qi = idx >> 5, kk = u * 32 + (idx & 31);
            if (kk >= W) continue;
            int q = row0 + qi;
            const float* src = P.plm + ((size_t)q * NTOK + (size_t)(kstart + kk)) * 16;
            float xv[16];
            *(float4*)(xv + 0)  = *(const float4*)(src + 0);
            *(float4*)(xv + 4)  = *(const float4*)(src + 4);
            *(float4*)(xv + 8)  = *(const float4*)(src + 8);
            *(float4*)(xv + 12) = *(const float4*)(src + 12);
            float s = 0.0f;
#pragma unroll
            for (int c = 0; c < 16; c++) s += xv[c];
            float mean = s * (1.0f / 16.0f);
            float var = 0.0f;
#pragma unroll
            for (int c = 0; c < 16; c++) { float d = xv[c] - mean; var += d * d; }
            float rs = 1.0f / sqrtf(var * (1.0f / 16.0f) + 1e-5f);
#pragma unroll
            for (int c = 0; c < 16; c++) xv[c] = (xv[c] - mean) * rs;
#pragma unroll
            for (int i3 = 0; i3 < NBLK; i3++) {
#pragma unroll
                for (int h = 0; h < 4; h++) {
                    float o = wzg[192 + i3 * 4 + h];
#pragma unroll
                    for (int c = 0; c < 16; c++) o = fmaf(xv[c], wzg[(i3 * 16 + c) * 4 + h], o);
                    P.zb[((size_t)(i3 * 4 + h) * NTOK + q) * 128 + kk] = o;
                }
            }
        }
    }
}

// ================= k2: local attention =================
// grid 768 = 8 XCD x 12 j x 4 h x 2 q-halves(16 rows)
__global__ __launch_bounds__(256) void k2_attn(Params P, int i)
{
    __shared__ __align__(16) float ks[128 * 36];
    __shared__ __align__(16) float vs[128 * 36];
    __shared__ float ps[16 * PSS];
    int tid = threadIdx.x, bid = blockIdx.x;
    int x8 = bid & 7, g = bid >> 3;            // 0..95
    int jl = g >> 3, rem = g & 7;
    int h = rem >> 1, qh = rem & 1;
    int jglob = x8 * 12 + jl;
    int q0 = jglob * 32 + qh * 16;
    int kstart = max(0, jglob * 32 - 48);
    int W = min(NTOK, jglob * 32 + 80) - kstart;
    for (int idx = tid; idx < W * 8; idx += 256) {
        int kk = idx >> 3, d = (idx & 7) * 4;
        const float* base = &P.qkvg[(size_t)(kstart + kk) * 512 + 128 + h * 32 + d];
        float4 tK = *(const float4*)base;
        float4 tV = *(const float4*)(base + 128);
        *(float4*)&ks[kk * 36 + d] = tK;
        *(float4*)&vs[kk * 36 + d] = tV;
    }
    const float* zbase = &P.zb[((size_t)(i * 4 + h) * NTOK + q0) * 128];
#pragma unroll
    for (int it = 0; it < 2; it++) {
        int idx = tid + it * 256;
        int r = idx >> 5, c4 = (idx & 31) * 4;
        float4 z4 = *(const float4*)&zbase[(size_t)r * 128 + c4];
        ps[r * PSS + c4]     = z4.x;
        ps[r * PSS + c4 + 1] = z4.y;
        ps[r * PSS + c4 + 2] = z4.z;
        ps[r * PSS + c4 + 3] = z4.w;
    }
    int qi = tid & 15, kg = tid >> 4;
    float qreg[32];
    {
        const float* qp = &P.qkvg[(size_t)(q0 + qi) * 512 + h * 32];
#pragma unroll
        for (int d4 = 0; d4 < 8; d4++) {
            float4 tq = *(const float4*)(qp + d4 * 4);
            qreg[d4 * 4] = tq.x; qreg[d4 * 4 + 1] = tq.y;
            qreg[d4 * 4 + 2] = tq.z; qreg[d4 * 4 + 3] = tq.w;
        }
    }
    __syncthreads();
    const float scale = 0.17677669529663687f;  // 1/sqrt(32)
#pragma unroll
    for (int t2 = 0; t2 < 8; t2++) {
        int kk = kg + t2 * 16;
        if (kk < W) {
            float acc = 0.0f;
#pragma unroll
            for (int d4 = 0; d4 < 8; d4++) {
                float4 kv = *(const float4*)&ks[kk * 36 + d4 * 4];
                acc = fmaf(qreg[d4 * 4 + 0], kv.x, acc);
                acc = fmaf(qreg[d4 * 4 + 1], kv.y, acc);
                acc = fmaf(qreg[d4 * 4 + 2], kv.z, acc);
                acc = fmaf(qreg[d4 * 4 + 3], kv.w, acc);
            }
            ps[qi * PSS + kk] = fmaf(acc, scale, ps[qi * PSS + kk]);
        }
    }
    __syncthreads();
    {
        int row = tid >> 4, sub = tid & 15;
        float m = -3.0e38f;
        for (int kk = sub; kk < W; kk += 16) m = fmaxf(m, ps[row * PSS + kk]);
#pragma unroll
        for (int s2 = 1; s2 < 16; s2 <<= 1) m = fmaxf(m, __shfl_xor(m, s2));
        float ssum = 0.0f;
        for (int kk = sub; kk < W; kk += 16) {
            float e = expf(ps[row * PSS + kk] - m);
            ps[row * PSS + kk] = e; ssum += e;
        }
#pragma unroll
        for (int s2 = 1; s2 < 16; s2 <<= 1) ssum += __shfl_xor(ssum, s2);
        float rinv = 1.0f / ssum;
        for (int kk = sub; kk < W; kk += 16) ps[row * PSS + kk] *= rinv;
    }
    __syncthreads();
    {
        int dg = tid >> 4, d0 = dg * 2;
        float o0 = 0.0f, o1 = 0.0f, o0b = 0.0f, o1b = 0.0f;
        for (int kk = 0; kk + 1 < W; kk += 2) {
            float p0 = ps[qi * PSS + kk], p1 = ps[qi * PSS + kk + 1];
            float2 va = *(const float2*)&vs[kk * 36 + d0];
            float2 vb = *(const float2*)&vs[(kk + 1) * 36 + d0];
            o0  = fmaf(p0, va.x, o0);  o1  = fmaf(p0, va.y, o1);
            o0b = fmaf(p1, vb.x, o0b); o1b = fmaf(p1, vb.y, o1b);
        }
        if (W & 1) {
            float p0 = ps[qi * PSS + W - 1];
            float2 va = *(const float2*)&vs[(W - 1) * 36 + d0];
            o0 = fmaf(p0, va.x, o0); o1 = fmaf(p0, va.y, o1);
        }
        o0 += o0b; o1 += o1b;
        float2 g2 = *(const float2*)&P.qkvg[(size_t)(q0 + qi) * 512 + 384 + h * 32 + d0];
        *(float2*)&P.attn[(size_t)(q0 + qi) * 128 + h * 32 + d0] =
            make_float2(o0 * sig(g2.x), o1 * sig(g2.y));
    }
}

// ================= k3: post (grid 384 = 8 XCD x 48 row-tiles(8)) =================
__global__ __launch_bounds__(256) void k3_post(Params P, int i)
{
    __shared__ __align__(16) float smA[8 * 132];   // LN(cl)
    __shared__ __align__(16) float smB[8 * 132];   // attn
    __shared__ __align__(16) float smC[8 * 260];   // ffb
    int tid = threadIdx.x, bid = blockIdx.x;
    int x8 = bid & 7, g = bid >> 3;
    int row0 = x8 * 384 + g * 8;
    int lane = tid & 63;
    int cq = (lane & 31) * 4;
    int r1 = tid >> 5;
    {
        int fo = tid * 4, r = fo >> 7, c = fo & 127;
        *(float4*)&smA[r * 132 + c] = *(const float4*)&P.cl[(size_t)(row0 + r) * 128 + c];
        *(float4*)&smB[r * 132 + c] = *(const float4*)&P.attn[(size_t)(row0 + r) * 128 + c];
    }
#pragma unroll
    for (int it = 0; it < 2; it++) {
        int fo = (tid + it * 256) * 4;
        int r = fo >> 8, c = fo & 255;
        *(float4*)&smC[r * 260 + c] = *(const float4*)&P.ffb[(size_t)(row0 + r) * 256 + c];
    }
    __syncthreads();
    {
        float4 c4 = *(float4*)&smA[r1 * 132 + cq];
        *(float4*)&smA[r1 * 132 + cq] = ln_row32(c4);
    }
    __syncthreads();
    const float* sgw  = P.sg_w  + (size_t)i * 16384 + cq;
    const float* sg2w = P.sg2_w + (size_t)i * 16384 + cq;
    const float* wo_i = P.wo    + (size_t)i * 16384 + cq;
    const float* f3   = P.ff3   + (size_t)i * 32768 + cq;
    float aG[4] = {}, aG2[4] = {}, aO[4] = {}, aT[4] = {};
#pragma unroll 2
    for (int k = 0; k < 128; k++) {
        float4 w1 = *(const float4*)(sgw  + (size_t)k * 128);
        float4 w2 = *(const float4*)(sg2w + (size_t)k * 128);
        float4 w3 = *(const float4*)(wo_i + (size_t)k * 128);
        float as = smA[r1 * 132 + k];
        float aa = smB[r1 * 132 + k];
        aG[0]  = fmaf(as, w1.x, aG[0]);  aG[1]  = fmaf(as, w1.y, aG[1]);
        aG[2]  = fmaf(as, w1.z, aG[2]);  aG[3]  = fmaf(as, w1.w, aG[3]);
        aG2[0] = fmaf(as, w2.x, aG2[0]); aG2[1] = fmaf(as, w2.y, aG2[1]);
        aG2[2] = fmaf(as, w2.z, aG2[2]); aG2[3] = fmaf(as, w2.w, aG2[3]);
        aO[0]  = fmaf(aa, w3.x, aO[0]);  aO[1]  = fmaf(aa, w3.y, aO[1]);
        aO[2]  = fmaf(aa, w3.z, aO[2]);  aO[3]  = fmaf(aa, w3.w, aO[3]);
    }
#pragma unroll 2
    for (int k = 0; k < 256; k++) {
        float4 w4 = *(const float4*)(f3 + (size_t)k * 128);
        float ac = smC[r1 * 260 + k];
        aT[0] = fmaf(ac, w4.x, aT[0]); aT[1] = fmaf(ac, w4.y, aT[1]);
        aT[2] = fmaf(ac, w4.z, aT[2]); aT[3] = fmaf(ac, w4.w, aT[3]);
    }
    float4 bv  = *(const float4*)&P.sg_b [(size_t)i * 128 + cq];
    float4 bv2 = *(const float4*)&P.sg2_b[(size_t)i * 128 + cq];
    float4 o;
    o.x = sig(aG[0] + bv.x) * aO[0] + sig(aG2[0] + bv2.x) * aT[0];
    o.y = sig(aG[1] + bv.y) * aO[1] + sig(aG2[1] + bv2.y) * aT[1];
    o.z = sig(aG[2] + bv.z) * aO[2] + sig(aG2[2] + bv2.z) * aT[2];
    o.w = sig(aG[3] + bv.w) * aO[3] + sig(aG2[3] + bv2.w) * aT[3];
    int row = row0 + r1;
    float* dst = (i == NBLK - 1) ? P.out : P.anew;
    *(float4*)&dst[(size_t)row * 128 + cq] = o;
}

extern "C" void kernel_launch(void* const* d_in, const int* in_sizes, int n_in,
                              void* d_out, int out_size, void* d_ws, size_t ws_size,
                              hipStream_t stream)
{
    Params P;
    P.ql       = (const float*)d_in[0];
    P.cl       = (const float*)d_in[1];
    P.plm      = (const float*)d_in[2];
    P.ada_g_w  = (const float*)d_in[3];
    P.ada_g_b  = (const float*)d_in[4];
    P.ada_b_w  = (const float*)d_in[5];
    P.wq       = (const float*)d_in[6];
    P.bq       = (const float*)d_in[7];
    P.wk       = (const float*)d_in[8];
    P.wv       = (const float*)d_in[9];
    P.z_ln_g   = (const float*)d_in[10];
    P.z_ln_b   = (const float*)d_in[11];
    P.wz       = (const float*)d_in[12];
    P.wg       = (const float*)d_in[13];
    P.wo       = (const float*)d_in[14];
    P.sg_w     = (const float*)d_in[15];
    P.sg_b     = (const float*)d_in[16];
    P.ada2_g_w = (const float*)d_in[17];
    P.ada2_g_b = (const float*)d_in[18];
    P.ada2_b_w = (const float*)d_in[19];
    P.ff1      = (const float*)d_in[20];
    P.ff2      = (const float*)d_in[21];
    P.ff3      = (const float*)d_in[22];
    P.sg2_w    = (const float*)d_in[23];
    P.sg2_b    = (const float*)d_in[24];

    float* ws = (float*)d_ws;
    const size_t NC = (size_t)NTOK * 128;
    P.anew = ws;
    P.attn = ws + NC;
    P.qkvg = ws + 2 * NC;   // N x 512
    P.ffb  = ws + 6 * NC;   // N x 256
    P.zb   = ws + 8 * NC;   // 3 x 4 x N x 128
    P.out  = (float*)d_out;

    for (int i = 0; i < NBLK; i++) {
        k1_pre<<<768, 256, 0, stream>>>(P, i);
        k2_attn<<<768, 256, 0, stream>>>(P, i);
        k3_post<<<384, 256, 0, stream>>>(P, i);
    }
}

// Round 8
// 306.564 us; speedup vs baseline: 1.4014x; 1.3556x over previous
//
#include <hip/hip_runtime.h>
#include <cmath>

#define NTOK 3072
#define NBLK 3
#define PSS 133   // ps LDS stride: %32 == 5 -> conflict-free reads

__device__ __forceinline__ float sig(float v) { return 1.0f / (1.0f + expf(-v)); }

struct Params {
    const float *ql, *cl, *plm;
    const float *ada_g_w, *ada_g_b, *ada_b_w;
    const float *wq, *bq, *wk, *wv;
    const float *z_ln_g, *z_ln_b, *wz;
    const float *wg, *wo, *sg_w, *sg_b;
    const float *ada2_g_w, *ada2_g_b, *ada2_b_w;
    const float *ff1, *ff2, *ff3, *sg2_w, *sg2_b;
    float *anew, *attn, *qkvg, *ffb, *zb, *G;
    float *out;
};

// 32-lane-subgroup row LN of 4 register values (cols (lane&31)*4 .. +3 of a 128-col row)
__device__ __forceinline__ float4 ln_row32(float4 v)
{
    float s = v.x + v.y + v.z + v.w;
#pragma unroll
    for (int m = 1; m < 32; m <<= 1) s += __shfl_xor(s, m);
    float mean = s * (1.0f / 128.0f);
    float d0 = v.x - mean, d1 = v.y - mean, d2 = v.z - mean, d3 = v.w - mean;
    float var = d0 * d0 + d1 * d1 + d2 * d2 + d3 * d3;
#pragma unroll
    for (int m = 1; m < 32; m <<= 1) var += __shfl_xor(var, m);
    float rs = 1.0f / sqrtf(var * (1.0f / 128.0f) + 1e-5f);
    return make_float4(d0 * rs, d1 * rs, d2 * rs, d3 * rs);
}

// ================= k0: all conditioning GEMMs (18 units) + pair bias zb =================
// blocks [0,1728): gemm: 8 XCD x 12 tiles(32 rows) x 18 units (6 kinds x 3 layers)
// blocks [1728,2112): zb: 8 XCD x 12 j x 4 kk-chunks
__global__ __launch_bounds__(256) void k0_cond(Params P)
{
    int tid = threadIdx.x, bid = blockIdx.x;
    const size_t NC = (size_t)NTOK * 128;
    if (bid < 1728) {
        __shared__ __align__(16) float smA[32 * 132];
        int x8 = bid & 7, rest = bid >> 3;          // rest 0..215
        int tl = rest % 12, unit = rest / 12;       // unit 0..17
        int kind = unit % 6, i = unit / 6;
        int row0 = (x8 * 12 + tl) * 32;
#pragma unroll
        for (int it = 0; it < 4; it++) {
            int fo = (tid + it * 256) * 4, r = fo >> 7, c = fo & 127;
            *(float4*)&smA[r * 132 + c] = *(const float4*)&P.cl[(size_t)(row0 + r) * 128 + c];
        }
        __syncthreads();
        int hw = tid >> 5, cq = (tid & 31) * 4;
#pragma unroll
        for (int rr = 0; rr < 4; rr++) {
            int r = hw * 4 + rr;
            float4 n = ln_row32(*(float4*)&smA[r * 132 + cq]);
            *(float4*)&smA[r * 132 + cq] = n;
        }
        __syncthreads();
        const float* W; const float* bias = nullptr; bool dosig = false;
        switch (kind) {
            case 0:  W = P.ada_g_w  + (size_t)i * 16384; bias = P.ada_g_b  + i * 128; dosig = true; break;
            case 1:  W = P.ada_b_w  + (size_t)i * 16384; break;
            case 2:  W = P.ada2_g_w + (size_t)i * 16384; bias = P.ada2_g_b + i * 128; dosig = true; break;
            case 3:  W = P.ada2_b_w + (size_t)i * 16384; break;
            case 4:  W = P.sg_w     + (size_t)i * 16384; bias = P.sg_b     + i * 128; dosig = true; break;
            default: W = P.sg2_w    + (size_t)i * 16384; bias = P.sg2_b    + i * 128; dosig = true; break;
        }
        W += cq;
        float acc[4][4] = {};
#pragma unroll 8
        for (int k = 0; k < 128; k++) {
            float4 w4 = *(const float4*)(W + (size_t)k * 128);
#pragma unroll
            for (int rr = 0; rr < 4; rr++) {
                float a = smA[(hw * 4 + rr) * 132 + k];
                acc[rr][0] = fmaf(a, w4.x, acc[rr][0]);
                acc[rr][1] = fmaf(a, w4.y, acc[rr][1]);
                acc[rr][2] = fmaf(a, w4.z, acc[rr][2]);
                acc[rr][3] = fmaf(a, w4.w, acc[rr][3]);
            }
        }
        float4 b4 = bias ? *(const float4*)&bias[cq] : make_float4(0, 0, 0, 0);
        float* dst = P.G + (size_t)(kind * NBLK + i) * NC;
#pragma unroll
        for (int rr = 0; rr < 4; rr++) {
            float4 o = make_float4(acc[rr][0] + b4.x, acc[rr][1] + b4.y,
                                   acc[rr][2] + b4.z, acc[rr][3] + b4.w);
            if (dosig) { o.x = sig(o.x); o.y = sig(o.y); o.z = sig(o.z); o.w = sig(o.w); }
            *(float4*)&dst[(size_t)(row0 + hw * 4 + rr) * 128 + cq] = o;
        }
    } else {
        __shared__ __align__(16) float wzg[204];
        int b2 = bid - 1728;
        int x8 = b2 & 7, rest = b2 >> 3;    // rest 0..47
        int jl = rest >> 2, kkc = rest & 3;
        int j = x8 * 12 + jl;
        if (tid < 192) {
            int i3 = tid >> 6, rem = tid & 63, c = rem >> 2, h = rem & 3;
            wzg[(i3 * 16 + c) * 4 + h] = P.z_ln_g[i3 * 16 + c] * P.wz[(i3 * 16 + c) * 4 + h];
        }
        if (tid < 12) {
            int i3 = tid >> 2, h = tid & 3;
            float s = 0.0f;
            for (int c = 0; c < 16; c++) s += P.z_ln_b[i3 * 16 + c] * P.wz[(i3 * 16 + c) * 4 + h];
            wzg[192 + tid] = s;
        }
        __syncthreads();
        int kstart = max(0, j * 32 - 48);
        int W = min(NTOK, j * 32 + 80) - kstart;
#pragma unroll
        for (int it = 0; it < 4; it++) {
            int idx = tid + it * 256;
            int qi = idx >> 5, kk = kkc * 32 + (idx & 31);
            if (kk >= W) continue;
            int q = j * 32 + qi;
            const float* src = P.plm + ((size_t)q * NTOK + (size_t)(kstart + kk)) * 16;
            float xv[16];
            *(float4*)(xv + 0)  = *(const float4*)(src + 0);
            *(float4*)(xv + 4)  = *(const float4*)(src + 4);
            *(float4*)(xv + 8)  = *(const float4*)(src + 8);
            *(float4*)(xv + 12) = *(const float4*)(src + 12);
            float s = 0.0f;
#pragma unroll
            for (int c = 0; c < 16; c++) s += xv[c];
            float mean = s * (1.0f / 16.0f);
            float var = 0.0f;
#pragma unroll
            for (int c = 0; c < 16; c++) { float d = xv[c] - mean; var += d * d; }
            float rs = 1.0f / sqrtf(var * (1.0f / 16.0f) + 1e-5f);
#pragma unroll
            for (int c = 0; c < 16; c++) xv[c] = (xv[c] - mean) * rs;
#pragma unroll
            for (int i3 = 0; i3 < NBLK; i3++) {
#pragma unroll
                for (int h = 0; h < 4; h++) {
                    float o = wzg[192 + i3 * 4 + h];
#pragma unroll
                    for (int c = 0; c < 16; c++) o = fmaf(xv[c], wzg[(i3 * 16 + c) * 4 + h], o);
                    P.zb[((size_t)(i3 * 4 + h) * NTOK + q) * 128 + kk] = o;
                }
            }
        }
    }
}

// ================= k1: x|y elementwise + single projection GEMM =================
// grid 576 = 8 XCD x 12 tiles(32 rows) x 6 units {q,k,v,g, ff-lo, ff-hi}
__global__ __launch_bounds__(256) void k1_pre(Params P, int i)
{
    __shared__ __align__(16) float smX[32 * 132];
    const size_t NC = (size_t)NTOK * 128;
    int tid = threadIdx.x, bid = blockIdx.x;
    int x8 = bid & 7, rest = bid >> 3;      // 0..71
    int tl = rest % 12, u = rest / 12;      // u 0..5
    int row0 = (x8 * 12 + tl) * 32;
    int hw = tid >> 5, cq = (tid & 31) * 4;
    const float* aprev = (i == 0) ? P.ql : P.anew;
    const float* Gg = P.G + (size_t)(((u < 4 ? 0 : 2) * NBLK) + i) * NC;
    const float* Gb = P.G + (size_t)(((u < 4 ? 1 : 3) * NBLK) + i) * NC;
#pragma unroll
    for (int rr = 0; rr < 4; rr++) {
        int r = row0 + hw * 4 + rr;
        float4 a4 = *(const float4*)&aprev[(size_t)r * 128 + cq];
        float4 ln4 = ln_row32(a4);
        float4 g4 = *(const float4*)&Gg[(size_t)r * 128 + cq];
        float4 b4 = *(const float4*)&Gb[(size_t)r * 128 + cq];
        float4 x4;
        x4.x = fmaf(g4.x, ln4.x, b4.x);
        x4.y = fmaf(g4.y, ln4.y, b4.y);
        x4.z = fmaf(g4.z, ln4.z, b4.z);
        x4.w = fmaf(g4.w, ln4.w, b4.w);
        *(float4*)&smX[(hw * 4 + rr) * 132 + cq] = x4;
    }
    __syncthreads();
    if (u < 4) {
        const float* W = (u == 0 ? P.wq : u == 1 ? P.wk : u == 2 ? P.wv : P.wg)
                         + (size_t)i * 16384 + cq;
        float acc[4][4] = {};
#pragma unroll 8
        for (int k = 0; k < 128; k++) {
            float4 w4 = *(const float4*)(W + (size_t)k * 128);
#pragma unroll
            for (int rr = 0; rr < 4; rr++) {
                float a = smX[(hw * 4 + rr) * 132 + k];
                acc[rr][0] = fmaf(a, w4.x, acc[rr][0]);
                acc[rr][1] = fmaf(a, w4.y, acc[rr][1]);
                acc[rr][2] = fmaf(a, w4.z, acc[rr][2]);
                acc[rr][3] = fmaf(a, w4.w, acc[rr][3]);
            }
        }
        float4 b4 = (u == 0) ? *(const float4*)&P.bq[(size_t)i * 128 + cq]
                             : make_float4(0, 0, 0, 0);
#pragma unroll
        for (int rr = 0; rr < 4; rr++) {
            int r = row0 + hw * 4 + rr;
            *(float4*)&P.qkvg[(size_t)r * 512 + u * 128 + cq] =
                make_float4(acc[rr][0] + b4.x, acc[rr][1] + b4.y,
                            acc[rr][2] + b4.z, acc[rr][3] + b4.w);
        }
    } else {
        int ch = (u - 4) * 128;
        const float* W1 = P.ff1 + (size_t)i * 32768 + ch + cq;
        const float* W2 = P.ff2 + (size_t)i * 32768 + ch + cq;
        float a1[4][4] = {}, a2[4][4] = {};
#pragma unroll 4
        for (int k = 0; k < 128; k++) {
            float4 w14 = *(const float4*)(W1 + (size_t)k * 256);
            float4 w24 = *(const float4*)(W2 + (size_t)k * 256);
#pragma unroll
            for (int rr = 0; rr < 4; rr++) {
                float a = smX[(hw * 4 + rr) * 132 + k];
                a1[rr][0] = fmaf(a, w14.x, a1[rr][0]);
                a1[rr][1] = fmaf(a, w14.y, a1[rr][1]);
                a1[rr][2] = fmaf(a, w14.z, a1[rr][2]);
                a1[rr][3] = fmaf(a, w14.w, a1[rr][3]);
                a2[rr][0] = fmaf(a, w24.x, a2[rr][0]);
                a2[rr][1] = fmaf(a, w24.y, a2[rr][1]);
                a2[rr][2] = fmaf(a, w24.z, a2[rr][2]);
                a2[rr][3] = fmaf(a, w24.w, a2[rr][3]);
            }
        }
#pragma unroll
        for (int rr = 0; rr < 4; rr++) {
            int r = row0 + hw * 4 + rr;
            float4 o;
            o.x = a1[rr][0] * sig(a1[rr][0]) * a2[rr][0];
            o.y = a1[rr][1] * sig(a1[rr][1]) * a2[rr][1];
            o.z = a1[rr][2] * sig(a1[rr][2]) * a2[rr][2];
            o.w = a1[rr][3] * sig(a1[rr][3]) * a2[rr][3];
            *(float4*)&P.ffb[(size_t)r * 256 + ch + cq] = o;
        }
    }
}

// ================= k2: local attention (grid 384 = 8 XCD x 12 j x 4 h) — R5 version ===========
__global__ __launch_bounds__(256) void k2_attn(Params P, int i)
{
    __shared__ __align__(16) float ks[128 * 36];
    __shared__ __align__(16) float vs[128 * 36];
    __shared__ float ps[32 * PSS];
    int tid = threadIdx.x, bid = blockIdx.x;
    int x8 = bid & 7, g = bid >> 3;
    int h = g / 12, jl = g % 12;
    int j = x8 * 12 + jl;
    int q0 = j * 32;
    int kstart = max(0, q0 - 48);
    int W = min(NTOK, q0 + 80) - kstart;
    for (int idx = tid; idx < W * 8; idx += 256) {
        int kk = idx >> 3, d = (idx & 7) * 4;
        const float* base = &P.qkvg[(size_t)(kstart + kk) * 512 + 128 + h * 32 + d];
        float4 tK = *(const float4*)base;
        float4 tV = *(const float4*)(base + 128);
        *(float4*)&ks[kk * 36 + d] = tK;
        *(float4*)&vs[kk * 36 + d] = tV;
    }
    const float* zbase = &P.zb[((size_t)(i * 4 + h) * NTOK + q0) * 128];
#pragma unroll
    for (int it = 0; it < 4; it++) {
        int idx = tid + it * 256;
        int r = idx >> 5, c4 = (idx & 31) * 4;
        float4 z4 = *(const float4*)&zbase[(size_t)r * 128 + c4];
        ps[r * PSS + c4]     = z4.x;
        ps[r * PSS + c4 + 1] = z4.y;
        ps[r * PSS + c4 + 2] = z4.z;
        ps[r * PSS + c4 + 3] = z4.w;
    }
    int qi = tid & 31, kg = tid >> 5;
    float qreg[32];
    {
        const float* qp = &P.qkvg[(size_t)(q0 + qi) * 512 + h * 32];
#pragma unroll
        for (int d4 = 0; d4 < 8; d4++) {
            float4 tq = *(const float4*)(qp + d4 * 4);
            qreg[d4 * 4] = tq.x; qreg[d4 * 4 + 1] = tq.y;
            qreg[d4 * 4 + 2] = tq.z; qreg[d4 * 4 + 3] = tq.w;
        }
    }
    __syncthreads();
    const float scale = 0.17677669529663687f;  // 1/sqrt(32)
#pragma unroll
    for (int t2 = 0; t2 < 16; t2++) {
        int kk = kg + t2 * 8;
        if (kk < W) {
            float acc = 0.0f;
#pragma unroll
            for (int d4 = 0; d4 < 8; d4++) {
                float4 kv = *(const float4*)&ks[kk * 36 + d4 * 4];
                acc = fmaf(qreg[d4 * 4 + 0], kv.x, acc);
                acc = fmaf(qreg[d4 * 4 + 1], kv.y, acc);
                acc = fmaf(qreg[d4 * 4 + 2], kv.z, acc);
                acc = fmaf(qreg[d4 * 4 + 3], kv.w, acc);
            }
            ps[qi * PSS + kk] = fmaf(acc, scale, ps[qi * PSS + kk]);
        }
    }
    __syncthreads();
    {
        int row = tid >> 3, sub = tid & 7;
        float m = -3.0e38f;
        for (int kk = sub; kk < W; kk += 8) m = fmaxf(m, ps[row * PSS + kk]);
#pragma unroll
        for (int s2 = 1; s2 < 8; s2 <<= 1) m = fmaxf(m, __shfl_xor(m, s2));
        float ssum = 0.0f;
        for (int kk = sub; kk < W; kk += 8) {
            float e = expf(ps[row * PSS + kk] - m);
            ps[row * PSS + kk] = e; ssum += e;
        }
#pragma unroll
        for (int s2 = 1; s2 < 8; s2 <<= 1) ssum += __shfl_xor(ssum, s2);
        float rinv = 1.0f / ssum;
        for (int kk = sub; kk < W; kk += 8) ps[row * PSS + kk] *= rinv;
    }
    __syncthreads();
    {
        int dg = tid >> 5, d0 = dg * 4;
        float o0 = 0, o1 = 0, o2 = 0, o3 = 0;
#pragma unroll 2
        for (int kk = 0; kk < W; kk++) {
            float pv = ps[qi * PSS + kk];
            float4 v4 = *(const float4*)&vs[kk * 36 + d0];
            o0 = fmaf(pv, v4.x, o0);
            o1 = fmaf(pv, v4.y, o1);
            o2 = fmaf(pv, v4.z, o2);
            o3 = fmaf(pv, v4.w, o3);
        }
        float4 g4 = *(const float4*)&P.qkvg[(size_t)(q0 + qi) * 512 + 384 + h * 32 + d0];
        float4 r;
        r.x = o0 * sig(g4.x); r.y = o1 * sig(g4.y);
        r.z = o2 * sig(g4.z); r.w = o3 * sig(g4.w);
        *(float4*)&P.attn[(size_t)(q0 + qi) * 128 + h * 32 + d0] = r;
    }
}

// ================= k3: wo + ff3 + precomputed gates =================
// grid 768 = 8 XCD x 24 tiles(16 rows) x 4 col-chunks(32)
__global__ __launch_bounds__(256) void k3_post(Params P, int i)
{
    __shared__ __align__(16) float smB[16 * 132];   // attn
    __shared__ __align__(16) float smC[16 * 260];   // ffb
    const size_t NC = (size_t)NTOK * 128;
    int tid = threadIdx.x, bid = blockIdx.x;
    int x8 = bid & 7, rest = bid >> 3;      // 0..95
    int tl = rest >> 2, cc = rest & 3;
    int row0 = x8 * 384 + tl * 16;
    int cbase = cc * 32;
#pragma unroll
    for (int it = 0; it < 2; it++) {
        int fo = (tid + it * 256) * 4, r = fo >> 7, c = fo & 127;
        *(float4*)&smB[r * 132 + c] = *(const float4*)&P.attn[(size_t)(row0 + r) * 128 + c];
    }
#pragma unroll
    for (int it = 0; it < 4; it++) {
        int fo = (tid + it * 256) * 4, r = fo >> 8, c = fo & 255;
        *(float4*)&smC[r * 260 + c] = *(const float4*)&P.ffb[(size_t)(row0 + r) * 256 + c];
    }
    __syncthreads();
    int r = tid >> 4, cl2 = (tid & 15) * 2;
    int c = cbase + cl2;
    const float* wo_p = P.wo  + (size_t)i * 16384 + c;
    const float* f3_p = P.ff3 + (size_t)i * 32768 + c;
    float aO0 = 0, aO1 = 0, aT0 = 0, aT1 = 0;
#pragma unroll 8
    for (int k = 0; k < 128; k++) {
        float2 w2 = *(const float2*)(wo_p + (size_t)k * 128);
        float a = smB[r * 132 + k];
        aO0 = fmaf(a, w2.x, aO0);
        aO1 = fmaf(a, w2.y, aO1);
    }
#pragma unroll 8
    for (int k = 0; k < 256; k++) {
        float2 w2 = *(const float2*)(f3_p + (size_t)k * 128);
        float a = smC[r * 260 + k];
        aT0 = fmaf(a, w2.x, aT0);
        aT1 = fmaf(a, w2.y, aT1);
    }
    int row = row0 + r;
    float2 sgv  = *(const float2*)&P.G[(size_t)(4 * NBLK + i) * NC + (size_t)row * 128 + c];
    float2 sg2v = *(const float2*)&P.G[(size_t)(5 * NBLK + i) * NC + (size_t)row * 128 + c];
    float2 o;
    o.x = sgv.x * aO0 + sg2v.x * aT0;
    o.y = sgv.y * aO1 + sg2v.y * aT1;
    float* dst = (i == NBLK - 1) ? P.out : P.anew;
    *(float2*)&dst[(size_t)row * 128 + c] = o;
}

extern "C" void kernel_launch(void* const* d_in, const int* in_sizes, int n_in,
                              void* d_out, int out_size, void* d_ws, size_t ws_size,
                              hipStream_t stream)
{
    Params P;
    P.ql       = (const float*)d_in[0];
    P.cl       = (const float*)d_in[1];
    P.plm      = (const float*)d_in[2];
    P.ada_g_w  = (const float*)d_in[3];
    P.ada_g_b  = (const float*)d_in[4];
    P.ada_b_w  = (const float*)d_in[5];
    P.wq       = (const float*)d_in[6];
    P.bq       = (const float*)d_in[7];
    P.wk       = (const float*)d_in[8];
    P.wv       = (const float*)d_in[9];
    P.z_ln_g   = (const float*)d_in[10];
    P.z_ln_b   = (const float*)d_in[11];
    P.wz       = (const float*)d_in[12];
    P.wg       = (const float*)d_in[13];
    P.wo       = (const float*)d_in[14];
    P.sg_w     = (const float*)d_in[15];
    P.sg_b     = (const float*)d_in[16];
    P.ada2_g_w = (const float*)d_in[17];
    P.ada2_g_b = (const float*)d_in[18];
    P.ada2_b_w = (const float*)d_in[19];
    P.ff1      = (const float*)d_in[20];
    P.ff2      = (const float*)d_in[21];
    P.ff3      = (const float*)d_in[22];
    P.sg2_w    = (const float*)d_in[23];
    P.sg2_b    = (const float*)d_in[24];

    float* ws = (float*)d_ws;
    const size_t NC = (size_t)NTOK * 128;
    P.anew = ws;
    P.attn = ws + NC;
    P.qkvg = ws + 2 * NC;    // N x 512
    P.ffb  = ws + 6 * NC;    // N x 256
    P.zb   = ws + 8 * NC;    // 3 x 4 x N x 128
    P.G    = ws + 20 * NC;   // 18 x N x 128 (6 kinds x 3 layers)
    P.out  = (float*)d_out;

    k0_cond<<<2112, 256, 0, stream>>>(P);
    for (int i = 0; i < NBLK; i++) {
        k1_pre<<<576, 256, 0, stream>>>(P, i);
        k2_attn<<<384, 256, 0, stream>>>(P, i);
        k3_post<<<768, 256, 0, stream>>>(P, i);
    }
}